// Round 1
// baseline (2542.847 us; speedup 1.0000x reference)
//
#include <hip/hip_runtime.h>

// Fused 5-layer MLP 203->175->150->128->80->48, tanh on 1-4, B=131072, fp32 I/O.
// Split-bf16 MFMA (v = hi+lo bf16; 3 MFMAs aH*bH + aL*bH + aH*bL), 32x32x16.
// R4: latency-bound fix. M=32 rows/block (grid 4096), 4-way N-split across the
// 4 waves -> actP LDS 22.5 KB -> 6-7 blocks/CU (was 3 @ 50 KB). Layer-1 xst
// staging DELETED: A-fragments read directly from global per-lane (x is
// L1/L2/L3-resident; FETCH_SIZE 58MB < |x| proved it) -> removes 25 of 33
// block-wide barriers + prefetch machinery. Numerics identical to R3.

typedef short short8 __attribute__((ext_vector_type(8)));
typedef float f32x16 __attribute__((ext_vector_type(16)));
typedef unsigned int uint;
typedef unsigned short ushort;

#define SROW 180    // actP stride (dwords): mod 32 = 20 -> period-8 full-bank b128

__device__ __forceinline__ ushort f2bf(float f) {
    uint u = __float_as_uint(f);
    u += 0x7FFFu + ((u >> 16) & 1u);
    return (ushort)(u >> 16);
}
__device__ __forceinline__ float bf2f(ushort h) { return __uint_as_float(((uint)h) << 16); }
__device__ __forceinline__ float fast_tanh(float x) {
    float e = __expf(2.0f * x);
    return 1.0f - 2.0f / (e + 1.0f);
}
__device__ __forceinline__ uint rbf(float v) {   // bf16-RNE rounded bits; hi16 = result>>16
    uint u = __float_as_uint(v);
    return u + 0x7FFFu + ((u >> 16) & 1u);
}

union U4S8 { uint4 u; short8 s; };

// ---------------- prep: split weights into ws in B-fragment order ------------
// (unchanged from R3 — verified correct.) Tile pair p = c*NT + t: 2048 B =
// [hi plane 1024B][lo plane 1024B], lane l holds B[k=(l>>5)*8+j][n=l&31].
__global__ void prep_weights(const float* __restrict__ W1, const float* __restrict__ W2,
                             const float* __restrict__ W3, const float* __restrict__ W4,
                             const float* __restrict__ W5, char* __restrict__ ws)
{
    const int b = blockIdx.x, l = threadIdx.x;   // 207 blocks x 64 threads
    int layer, local;
    if      (b <  78) { layer = 0; local = b; }
    else if (b < 133) { layer = 1; local = b - 78; }
    else if (b < 173) { layer = 2; local = b - 133; }
    else if (b < 197) { layer = 3; local = b - 173; }
    else              { layer = 4; local = b - 197; }
    const int NTa[5]  = {6, 5, 4, 3, 2};
    const int FINa[5] = {203, 175, 150, 128, 80};
    const int FOa[5]  = {175, 150, 128, 80, 48};
    const float* Wp = (layer == 0) ? W1 : (layer == 1) ? W2 : (layer == 2) ? W3
                    : (layer == 3) ? W4 : W5;
    const int nt = NTa[layer], fin = FINa[layer], fout = FOa[layer];
    const int c = local / nt, t = local % nt;
    const int n  = t * 32 + (l & 31);
    const int kb = c * 16 + (l >> 5) * 8;
    uint hw[4], lw[4];
#pragma unroll
    for (int j = 0; j < 8; ++j) {
        int k = kb + j;
        float v = (n < fout && k < fin) ? Wp[(size_t)n * fin + k] : 0.0f;
        ushort hh = f2bf(v);
        ushort ll = f2bf(v - bf2f(hh));
        if (j & 1) { hw[j >> 1] |= ((uint)hh) << 16; lw[j >> 1] |= ((uint)ll) << 16; }
        else       { hw[j >> 1]  = hh;               lw[j >> 1]  = ll; }
    }
    char* dst = ws + (size_t)b * 2048 + l * 16;
    *(uint4*)dst          = make_uint4(hw[0], hw[1], hw[2], hw[3]);
    *(uint4*)(dst + 1024) = make_uint4(lw[0], lw[1], lw[2], lw[3]);
}

// ---------------- D-phase: acc -> tanh -> packed actP (or global out) --------
// M=32: rowl = (r&3) + 8*(r>>2) + 4*lh; tiles t = ns + 4*m.
template<int MT, int NT, int FOUT, int PADN, bool ACT, bool LAST>
__device__ __forceinline__ void d_phase(f32x16* acc, uint* oP, float* outg,
                                        int row0, int ns, int lx, int lh, int tid)
{
#pragma unroll
    for (int m = 0; m < MT; ++m) {
        int t = ns + 4 * m;
        if (t < NT) {
#pragma unroll
            for (int r = 0; r < 16; ++r) {
                float vv = acc[m][r];
                if (ACT) vv = fast_tanh(vv);
                int rowl = (r & 3) + 8 * (r >> 2) + 4 * lh;
                int col  = t * 32 + lx;
                if (LAST) {
                    if (col < 48) outg[(size_t)(row0 + rowl) * 48 + col] = vv;
                } else if (col < FOUT) {
                    uint r1  = rbf(vv);
                    uint hib = r1 & 0xFFFF0000u;
                    float lo = vv - __uint_as_float(hib);
                    uint r2  = rbf(lo);
                    oP[rowl * SROW + col] = hib | (r2 >> 16);   // hi in high16, lo in low16
                }
            }
        }
    }
    if (!LAST) {
        if (PADN > 0) {
            for (int idx = tid; idx < 32 * PADN; idx += 256) {
                int row = idx / PADN, p = idx % PADN;
                oP[row * SROW + FOUT + p] = 0u;
            }
        }
        __syncthreads();    // post-D: outputs visible to next layer
    }
}

// ---------------- layers 2-5: A from packed actP, B direct from global -------
template<int KC, int NT, int FOUT, int PADN, bool ACT, bool LAST>
__device__ __forceinline__ void run_layer(const char* __restrict__ wsL,
    const float* __restrict__ bias, const uint* aP, uint* oP, float* outg,
    int row0, int l, int ns, int lx, int lh, int tid)
{
    constexpr int MT = (NT + 3) / 4;
    f32x16 acc[MT];
#pragma unroll
    for (int m = 0; m < MT; ++m) {
        int t = ns + 4 * m;
        float bv = 0.0f;
        if (t < NT) { int n = t * 32 + lx; bv = (n < FOUT) ? bias[n] : 0.0f; }
#pragma unroll
        for (int r = 0; r < 16; ++r) acc[m][r] = bv;
    }

    if (ns < NT) {   // waves with no tile skip the whole K-loop (uniform branch)
#pragma unroll
        for (int c = 0; c < KC; ++c) {
            U4S8 bh[MT], bl[MT];
#pragma unroll
            for (int m = 0; m < MT; ++m) {
                int t = ns + 4 * m;
                if (t < NT) {
                    const uint4* w = (const uint4*)wsL + (size_t)((c * NT + t) * 2) * 64 + l;
                    bh[m].u = w[0];      // hi plane (1024 B = 64 uint4)
                    bl[m].u = w[64];     // lo plane
                }
            }
            const uint* ap = aP + lx * SROW + c * 16 + lh * 8;
            uint4 d0 = *(const uint4*)ap;          // ds_read_b128, 16B-aligned
            uint4 d1 = *(const uint4*)(ap + 4);
            uint dd[8] = {d0.x, d0.y, d0.z, d0.w, d1.x, d1.y, d1.z, d1.w};
            U4S8 ah, al;
            uint* aHu = (uint*)&ah; uint* aLu = (uint*)&al;
#pragma unroll
            for (int j = 0; j < 4; ++j) {
                aHu[j] = (dd[2*j] >> 16)     | (dd[2*j + 1] & 0xFFFF0000u);
                aLu[j] = (dd[2*j] & 0xFFFFu) | (dd[2*j + 1] << 16);
            }
#pragma unroll
            for (int m = 0; m < MT; ++m) {
                int t = ns + 4 * m;
                if (t < NT) {
                    acc[m] = __builtin_amdgcn_mfma_f32_32x32x16_bf16(ah.s, bh[m].s, acc[m], 0, 0, 0);
                    acc[m] = __builtin_amdgcn_mfma_f32_32x32x16_bf16(al.s, bh[m].s, acc[m], 0, 0, 0);
                    acc[m] = __builtin_amdgcn_mfma_f32_32x32x16_bf16(ah.s, bl[m].s, acc[m], 0, 0, 0);
                }
            }
        }
    }
    if (!LAST) __syncthreads();   // pre-D: all actP reads done before overwrite
    d_phase<MT, NT, FOUT, PADN, ACT, LAST>(acc, oP, outg, row0, ns, lx, lh, tid);
}

// ---------------- layer 1: A-fragments straight from global (x cache-fed) ----
__device__ __forceinline__ void run_first(const float* __restrict__ x,
    const char* __restrict__ wsL, const float* __restrict__ bias,
    uint* oP, int row0, int l, int ns, int lx, int lh, int tid)
{
    constexpr int KC = 13, NT = 6, MT = 2;
    f32x16 acc[MT];
#pragma unroll
    for (int m = 0; m < MT; ++m) {
        int t = ns + 4 * m;
        float bv = 0.0f;
        if (t < NT) { int n = t * 32 + lx; bv = (n < 175) ? bias[n] : 0.0f; }
#pragma unroll
        for (int r = 0; r < 16; ++r) acc[m][r] = bv;
    }

    // per-lane row pointer; rows are 203 floats (odd) -> scalar dword loads
    // (16B vectors would be misaligned). All chunks except c=12 are in-bounds.
    const float* xr = x + (size_t)(row0 + lx) * 203 + lh * 8;

#pragma unroll
    for (int c = 0; c < KC; ++c) {
        U4S8 bh[MT], bl[MT];
#pragma unroll
        for (int m = 0; m < MT; ++m) {
            int t = ns + 4 * m;
            if (t < NT) {
                const uint4* w = (const uint4*)wsL + (size_t)((c * NT + t) * 2) * 64 + l;
                bh[m].u = w[0];
                bl[m].u = w[64];
            }
        }
        float vv[8];
#pragma unroll
        for (int j = 0; j < 8; ++j) {
            if (c < 12) {
                vv[j] = xr[c * 16 + j];
            } else {
                int k = c * 16 + lh * 8 + j;             // 192..207
                vv[j] = (k < 203) ? xr[c * 16 + j] : 0.0f;
            }
        }
        uint rh[8], rl[8];
#pragma unroll
        for (int j = 0; j < 8; ++j) {
            rh[j] = rbf(vv[j]);
            float lo = vv[j] - __uint_as_float(rh[j] & 0xFFFF0000u);
            rl[j] = rbf(lo);
        }
        U4S8 ah, al;
        uint* aHu = (uint*)&ah; uint* aLu = (uint*)&al;
#pragma unroll
        for (int j = 0; j < 4; ++j) {
            aHu[j] = (rh[2*j] >> 16) | (rh[2*j + 1] & 0xFFFF0000u);
            aLu[j] = (rl[2*j] >> 16) | (rl[2*j + 1] & 0xFFFF0000u);
        }
#pragma unroll
        for (int m = 0; m < MT; ++m) {
            int t = ns + 4 * m;
            if (t < NT) {
                acc[m] = __builtin_amdgcn_mfma_f32_32x32x16_bf16(ah.s, bh[m].s, acc[m], 0, 0, 0);
                acc[m] = __builtin_amdgcn_mfma_f32_32x32x16_bf16(al.s, bh[m].s, acc[m], 0, 0, 0);
                acc[m] = __builtin_amdgcn_mfma_f32_32x32x16_bf16(ah.s, bl[m].s, acc[m], 0, 0, 0);
            }
        }
    }
    // no pre-D barrier: actP untouched so far; d_phase ends with post-D barrier
    d_phase<MT, NT, 175, 1, true, false>(acc, oP, nullptr, row0, ns, lx, lh, tid);
}

__global__ __launch_bounds__(256, 6)
void mlp_mfma(const float* __restrict__ x,
              const float* __restrict__ b1, const float* __restrict__ b2,
              const float* __restrict__ b3, const float* __restrict__ b4,
              const float* __restrict__ b5,
              const char* __restrict__ ws, float* __restrict__ out)
{
    __shared__ __align__(16) uint actP[32 * SROW];   // 23040 B -> 6-7 blocks/CU

    const int tid = threadIdx.x;
    const int l = tid & 63, w = tid >> 6;
    const int ns = w;                 // 4-way N-split, single 32-row group
    const int lx = l & 31, lh = l >> 5;
    const int row0 = blockIdx.x * 32;

    run_first(x, ws, b1, actP, row0, l, ns, lx, lh, tid);
    run_layer<11, 5, 150, 10, true,  false>(ws +  78 * 2048, b2, actP, actP, nullptr, row0, l, ns, lx, lh, tid);
    run_layer<10, 4, 128,  0, true,  false>(ws + 133 * 2048, b3, actP, actP, nullptr, row0, l, ns, lx, lh, tid);
    run_layer< 8, 3,  80,  0, true,  false>(ws + 173 * 2048, b4, actP, actP, nullptr, row0, l, ns, lx, lh, tid);
    run_layer< 5, 2,  48,  0, false, true >(ws + 197 * 2048, b5, actP, actP, out,     row0, l, ns, lx, lh, tid);
}

extern "C" void kernel_launch(void* const* d_in, const int* in_sizes, int n_in,
                              void* d_out, int out_size, void* d_ws, size_t ws_size,
                              hipStream_t stream) {
    (void)in_sizes; (void)n_in; (void)ws_size; (void)out_size;
    const float* x  = (const float*)d_in[0];
    const float* W1 = (const float*)d_in[1];
    const float* b1 = (const float*)d_in[2];
    const float* W2 = (const float*)d_in[3];
    const float* b2 = (const float*)d_in[4];
    const float* W3 = (const float*)d_in[5];
    const float* b3 = (const float*)d_in[6];
    const float* W4 = (const float*)d_in[7];
    const float* b4 = (const float*)d_in[8];
    const float* W5 = (const float*)d_in[9];
    const float* b5 = (const float*)d_in[10];
    float* out = (float*)d_out;
    char* ws = (char*)d_ws;      // needs 423936 B (verified fits in R2)

    hipLaunchKernelGGL(prep_weights, dim3(207), dim3(64), 0, stream,
                       W1, W2, W3, W4, W5, ws);
    hipLaunchKernelGGL(mlp_mfma, dim3(131072 / 32), dim3(256), 0, stream,
                       x, b1, b2, b3, b4, b5, ws, out);
}

// Round 2
// 596.264 us; speedup vs baseline: 4.2646x; 4.2646x over previous
//
#include <hip/hip_runtime.h>

// Fused 5-layer MLP 203->175->150->128->80->48, tanh on 1-4, B=131072, fp32 I/O.
// Split-bf16 MFMA (v = hi+lo bf16; 3 MFMAs aH*bH + aL*bH + aH*bL), 32x32x16.
// R5: R4 structure (M=32/block, grid 4096, 4-way N-split, actP 22.5 KB, no xst
// staging) with the spill fixed: __launch_bounds__(256,4) (VGPR cap 128, live
// set ~90) instead of (256,6) (cap 84 -> accumulator tuples spilled to scratch,
// 11.5 GB HBM scratch traffic, 2.46 ms). Occupancy now min(LDS 6, VGPR ~5)
// blocks/CU ~= 62% vs R3's 3 blocks @ 30%.

typedef short short8 __attribute__((ext_vector_type(8)));
typedef float f32x16 __attribute__((ext_vector_type(16)));
typedef unsigned int uint;
typedef unsigned short ushort;

#define SROW 180    // actP stride (dwords): mod 32 = 20 -> period-8 full-bank b128

__device__ __forceinline__ ushort f2bf(float f) {
    uint u = __float_as_uint(f);
    u += 0x7FFFu + ((u >> 16) & 1u);
    return (ushort)(u >> 16);
}
__device__ __forceinline__ float bf2f(ushort h) { return __uint_as_float(((uint)h) << 16); }
__device__ __forceinline__ float fast_tanh(float x) {
    float e = __expf(2.0f * x);
    return 1.0f - 2.0f / (e + 1.0f);
}
__device__ __forceinline__ uint rbf(float v) {   // bf16-RNE rounded bits; hi16 = result>>16
    uint u = __float_as_uint(v);
    return u + 0x7FFFu + ((u >> 16) & 1u);
}

union U4S8 { uint4 u; short8 s; };

// ---------------- prep: split weights into ws in B-fragment order ------------
// (unchanged — verified correct.) Tile pair p = c*NT + t: 2048 B =
// [hi plane 1024B][lo plane 1024B], lane l holds B[k=(l>>5)*8+j][n=l&31].
__global__ void prep_weights(const float* __restrict__ W1, const float* __restrict__ W2,
                             const float* __restrict__ W3, const float* __restrict__ W4,
                             const float* __restrict__ W5, char* __restrict__ ws)
{
    const int b = blockIdx.x, l = threadIdx.x;   // 207 blocks x 64 threads
    int layer, local;
    if      (b <  78) { layer = 0; local = b; }
    else if (b < 133) { layer = 1; local = b - 78; }
    else if (b < 173) { layer = 2; local = b - 133; }
    else if (b < 197) { layer = 3; local = b - 173; }
    else              { layer = 4; local = b - 197; }
    const int NTa[5]  = {6, 5, 4, 3, 2};
    const int FINa[5] = {203, 175, 150, 128, 80};
    const int FOa[5]  = {175, 150, 128, 80, 48};
    const float* Wp = (layer == 0) ? W1 : (layer == 1) ? W2 : (layer == 2) ? W3
                    : (layer == 3) ? W4 : W5;
    const int nt = NTa[layer], fin = FINa[layer], fout = FOa[layer];
    const int c = local / nt, t = local % nt;
    const int n  = t * 32 + (l & 31);
    const int kb = c * 16 + (l >> 5) * 8;
    uint hw[4], lw[4];
#pragma unroll
    for (int j = 0; j < 8; ++j) {
        int k = kb + j;
        float v = (n < fout && k < fin) ? Wp[(size_t)n * fin + k] : 0.0f;
        ushort hh = f2bf(v);
        ushort ll = f2bf(v - bf2f(hh));
        if (j & 1) { hw[j >> 1] |= ((uint)hh) << 16; lw[j >> 1] |= ((uint)ll) << 16; }
        else       { hw[j >> 1]  = hh;               lw[j >> 1]  = ll; }
    }
    char* dst = ws + (size_t)b * 2048 + l * 16;
    *(uint4*)dst          = make_uint4(hw[0], hw[1], hw[2], hw[3]);
    *(uint4*)(dst + 1024) = make_uint4(lw[0], lw[1], lw[2], lw[3]);
}

// ---------------- D-phase: acc -> tanh -> packed actP (or global out) --------
// M=32: rowl = (r&3) + 8*(r>>2) + 4*lh; tiles t = ns + 4*m.
template<int MT, int NT, int FOUT, int PADN, bool ACT, bool LAST>
__device__ __forceinline__ void d_phase(f32x16* acc, uint* oP, float* outg,
                                        int row0, int ns, int lx, int lh, int tid)
{
#pragma unroll
    for (int m = 0; m < MT; ++m) {
        int t = ns + 4 * m;
        if (t < NT) {
#pragma unroll
            for (int r = 0; r < 16; ++r) {
                float vv = acc[m][r];
                if (ACT) vv = fast_tanh(vv);
                int rowl = (r & 3) + 8 * (r >> 2) + 4 * lh;
                int col  = t * 32 + lx;
                if (LAST) {
                    if (col < 48) outg[(size_t)(row0 + rowl) * 48 + col] = vv;
                } else if (col < FOUT) {
                    uint r1  = rbf(vv);
                    uint hib = r1 & 0xFFFF0000u;
                    float lo = vv - __uint_as_float(hib);
                    uint r2  = rbf(lo);
                    oP[rowl * SROW + col] = hib | (r2 >> 16);   // hi in high16, lo in low16
                }
            }
        }
    }
    if (!LAST) {
        if (PADN > 0) {
            for (int idx = tid; idx < 32 * PADN; idx += 256) {
                int row = idx / PADN, p = idx % PADN;
                oP[row * SROW + FOUT + p] = 0u;
            }
        }
        __syncthreads();    // post-D: outputs visible to next layer
    }
}

// ---------------- layers 2-5: A from packed actP, B direct from global -------
template<int KC, int NT, int FOUT, int PADN, bool ACT, bool LAST>
__device__ __forceinline__ void run_layer(const char* __restrict__ wsL,
    const float* __restrict__ bias, const uint* aP, uint* oP, float* outg,
    int row0, int l, int ns, int lx, int lh, int tid)
{
    constexpr int MT = (NT + 3) / 4;
    f32x16 acc[MT];
#pragma unroll
    for (int m = 0; m < MT; ++m) {
        int t = ns + 4 * m;
        float bv = 0.0f;
        if (t < NT) { int n = t * 32 + lx; bv = (n < FOUT) ? bias[n] : 0.0f; }
#pragma unroll
        for (int r = 0; r < 16; ++r) acc[m][r] = bv;
    }

    if (ns < NT) {   // waves with no tile skip the whole K-loop (uniform branch)
#pragma unroll
        for (int c = 0; c < KC; ++c) {
            U4S8 bh[MT], bl[MT];
#pragma unroll
            for (int m = 0; m < MT; ++m) {
                int t = ns + 4 * m;
                if (t < NT) {
                    const uint4* w = (const uint4*)wsL + (size_t)((c * NT + t) * 2) * 64 + l;
                    bh[m].u = w[0];      // hi plane (1024 B = 64 uint4)
                    bl[m].u = w[64];     // lo plane
                }
            }
            const uint* ap = aP + lx * SROW + c * 16 + lh * 8;
            uint4 d0 = *(const uint4*)ap;          // ds_read_b128, 16B-aligned
            uint4 d1 = *(const uint4*)(ap + 4);
            uint dd[8] = {d0.x, d0.y, d0.z, d0.w, d1.x, d1.y, d1.z, d1.w};
            U4S8 ah, al;
            uint* aHu = (uint*)&ah; uint* aLu = (uint*)&al;
#pragma unroll
            for (int j = 0; j < 4; ++j) {
                aHu[j] = (dd[2*j] >> 16)     | (dd[2*j + 1] & 0xFFFF0000u);
                aLu[j] = (dd[2*j] & 0xFFFFu) | (dd[2*j + 1] << 16);
            }
#pragma unroll
            for (int m = 0; m < MT; ++m) {
                int t = ns + 4 * m;
                if (t < NT) {
                    acc[m] = __builtin_amdgcn_mfma_f32_32x32x16_bf16(ah.s, bh[m].s, acc[m], 0, 0, 0);
                    acc[m] = __builtin_amdgcn_mfma_f32_32x32x16_bf16(al.s, bh[m].s, acc[m], 0, 0, 0);
                    acc[m] = __builtin_amdgcn_mfma_f32_32x32x16_bf16(ah.s, bl[m].s, acc[m], 0, 0, 0);
                }
            }
        }
    }
    if (!LAST) __syncthreads();   // pre-D: all actP reads done before overwrite
    d_phase<MT, NT, FOUT, PADN, ACT, LAST>(acc, oP, outg, row0, ns, lx, lh, tid);
}

// ---------------- layer 1: A-fragments straight from global (x cache-fed) ----
__device__ __forceinline__ void run_first(const float* __restrict__ x,
    const char* __restrict__ wsL, const float* __restrict__ bias,
    uint* oP, int row0, int l, int ns, int lx, int lh, int tid)
{
    constexpr int KC = 13, NT = 6, MT = 2;
    f32x16 acc[MT];
#pragma unroll
    for (int m = 0; m < MT; ++m) {
        int t = ns + 4 * m;
        float bv = 0.0f;
        if (t < NT) { int n = t * 32 + lx; bv = (n < 175) ? bias[n] : 0.0f; }
#pragma unroll
        for (int r = 0; r < 16; ++r) acc[m][r] = bv;
    }

    // per-lane row pointer; rows are 203 floats (odd) -> scalar dword loads
    // (16B vectors would be misaligned). All chunks except c=12 are in-bounds.
    const float* xr = x + (size_t)(row0 + lx) * 203 + lh * 8;

#pragma unroll
    for (int c = 0; c < KC; ++c) {
        U4S8 bh[MT], bl[MT];
#pragma unroll
        for (int m = 0; m < MT; ++m) {
            int t = ns + 4 * m;
            if (t < NT) {
                const uint4* w = (const uint4*)wsL + (size_t)((c * 6 + t) * 2) * 64 + l;
                bh[m].u = w[0];
                bl[m].u = w[64];
            }
        }
        float vv[8];
#pragma unroll
        for (int j = 0; j < 8; ++j) {
            if (c < 12) {
                vv[j] = xr[c * 16 + j];
            } else {
                int k = c * 16 + lh * 8 + j;             // 192..207
                vv[j] = (k < 203) ? xr[c * 16 + j] : 0.0f;
            }
        }
        uint rh[8], rl[8];
#pragma unroll
        for (int j = 0; j < 8; ++j) {
            rh[j] = rbf(vv[j]);
            float lo = vv[j] - __uint_as_float(rh[j] & 0xFFFF0000u);
            rl[j] = rbf(lo);
        }
        U4S8 ah, al;
        uint* aHu = (uint*)&ah; uint* aLu = (uint*)&al;
#pragma unroll
        for (int j = 0; j < 4; ++j) {
            aHu[j] = (rh[2*j] >> 16) | (rh[2*j + 1] & 0xFFFF0000u);
            aLu[j] = (rl[2*j] >> 16) | (rl[2*j + 1] & 0xFFFF0000u);
        }
#pragma unroll
        for (int m = 0; m < MT; ++m) {
            int t = ns + 4 * m;
            if (t < NT) {
                acc[m] = __builtin_amdgcn_mfma_f32_32x32x16_bf16(ah.s, bh[m].s, acc[m], 0, 0, 0);
                acc[m] = __builtin_amdgcn_mfma_f32_32x32x16_bf16(al.s, bh[m].s, acc[m], 0, 0, 0);
                acc[m] = __builtin_amdgcn_mfma_f32_32x32x16_bf16(ah.s, bl[m].s, acc[m], 0, 0, 0);
            }
        }
    }
    // no pre-D barrier: actP untouched so far; d_phase ends with post-D barrier
    d_phase<MT, NT, 175, 1, true, false>(acc, oP, nullptr, row0, ns, lx, lh, tid);
}

__global__ __launch_bounds__(256, 4)
void mlp_mfma(const float* __restrict__ x,
              const float* __restrict__ b1, const float* __restrict__ b2,
              const float* __restrict__ b3, const float* __restrict__ b4,
              const float* __restrict__ b5,
              const char* __restrict__ ws, float* __restrict__ out)
{
    __shared__ __align__(16) uint actP[32 * SROW];   // 23040 B

    const int tid = threadIdx.x;
    const int l = tid & 63, w = tid >> 6;
    const int ns = w;                 // 4-way N-split, single 32-row group
    const int lx = l & 31, lh = l >> 5;
    const int row0 = blockIdx.x * 32;

    run_first(x, ws, b1, actP, row0, l, ns, lx, lh, tid);
    run_layer<11, 5, 150, 10, true,  false>(ws +  78 * 2048, b2, actP, actP, nullptr, row0, l, ns, lx, lh, tid);
    run_layer<10, 4, 128,  0, true,  false>(ws + 133 * 2048, b3, actP, actP, nullptr, row0, l, ns, lx, lh, tid);
    run_layer< 8, 3,  80,  0, true,  false>(ws + 173 * 2048, b4, actP, actP, nullptr, row0, l, ns, lx, lh, tid);
    run_layer< 5, 2,  48,  0, false, true >(ws + 197 * 2048, b5, actP, actP, out,     row0, l, ns, lx, lh, tid);
}

extern "C" void kernel_launch(void* const* d_in, const int* in_sizes, int n_in,
                              void* d_out, int out_size, void* d_ws, size_t ws_size,
                              hipStream_t stream) {
    (void)in_sizes; (void)n_in; (void)ws_size; (void)out_size;
    const float* x  = (const float*)d_in[0];
    const float* W1 = (const float*)d_in[1];
    const float* b1 = (const float*)d_in[2];
    const float* W2 = (const float*)d_in[3];
    const float* b2 = (const float*)d_in[4];
    const float* W3 = (const float*)d_in[5];
    const float* b3 = (const float*)d_in[6];
    const float* W4 = (const float*)d_in[7];
    const float* b4 = (const float*)d_in[8];
    const float* W5 = (const float*)d_in[9];
    const float* b5 = (const float*)d_in[10];
    float* out = (float*)d_out;
    char* ws = (char*)d_ws;      // needs 423936 B (verified fits in R2)

    hipLaunchKernelGGL(prep_weights, dim3(207), dim3(64), 0, stream,
                       W1, W2, W3, W4, W5, ws);
    hipLaunchKernelGGL(mlp_mfma, dim3(131072 / 32), dim3(256), 0, stream,
                       x, b1, b2, b3, b4, b5, ws, out);
}

// Round 3
// 326.862 us; speedup vs baseline: 7.7796x; 1.8242x over previous
//
#include <hip/hip_runtime.h>

// Fused 5-layer MLP 203->175->150->128->80->48, tanh on 1-4, B=131072, fp32 I/O.
// Split-bf16 MFMA (v = hi+lo bf16; 3 MFMAs aH*bH + aL*bH + aH*bL), 32x32x16.
// R6: register-demand fix + L1 repack dedup.
//  - 384 threads (6 waves), M=32 rows, grid 4096. Wave w owns tile t=w -> MT=1
//    in ALL layers: one f32x16 acc (16 AGPR) + one weight-frag pair. Demand
//    ~90 regs < cap 102 from __launch_bounds__(384,5). (R4/R5 lesson: rocprof
//    VGPR_Count excludes AGPRs; R5's 64 arch + 64 acc == cap 128 -> spilled
//    587 MB of scratch writes. MT=2 can never fit 4 waves/EU.)
//  - x is split-converted ONCE per block into a packed hi|lo LDS plane (stride
//    212 dwords, mod 32 = 20 -> same conflict-free b128 pattern as actP), so
//    layer 1 == layers 2-5 structurally. Kills the 6x-replicated per-wave
//    repack (~5400 wave-inst/block, the largest VALU item in R5).
//  - Stage buffer unions with actP (27.1 KB LDS): actP writes happen after the
//    pre-D barrier, after all x reads. Numerics bit-identical to R3/R5.

typedef short short8 __attribute__((ext_vector_type(8)));
typedef float f32x16 __attribute__((ext_vector_type(16)));
typedef unsigned int uint;
typedef unsigned short ushort;

#define SROW 180       // actP stride (dwords): mod 32 = 20 -> period-8 full-bank b128
#define XROW 212       // staged-x stride (dwords): mod 32 = 20 -> same good pattern
#define NTHREADS 384

__device__ __forceinline__ ushort f2bf(float f) {
    uint u = __float_as_uint(f);
    u += 0x7FFFu + ((u >> 16) & 1u);
    return (ushort)(u >> 16);
}
__device__ __forceinline__ float bf2f(ushort h) { return __uint_as_float(((uint)h) << 16); }
__device__ __forceinline__ float fast_tanh(float x) {
    float e = __expf(2.0f * x);
    return 1.0f - 2.0f / (e + 1.0f);
}
__device__ __forceinline__ uint rbf(float v) {   // bf16-RNE rounded bits; hi16 = result>>16
    uint u = __float_as_uint(v);
    return u + 0x7FFFu + ((u >> 16) & 1u);
}

union U4S8 { uint4 u; short8 s; };

// ---------------- prep: split weights into ws in B-fragment order ------------
// (unchanged — verified correct.) Tile pair p = c*NT + t: 2048 B =
// [hi plane 1024B][lo plane 1024B], lane l holds B[k=(l>>5)*8+j][n=l&31].
__global__ void prep_weights(const float* __restrict__ W1, const float* __restrict__ W2,
                             const float* __restrict__ W3, const float* __restrict__ W4,
                             const float* __restrict__ W5, char* __restrict__ ws)
{
    const int b = blockIdx.x, l = threadIdx.x;   // 207 blocks x 64 threads
    int layer, local;
    if      (b <  78) { layer = 0; local = b; }
    else if (b < 133) { layer = 1; local = b - 78; }
    else if (b < 173) { layer = 2; local = b - 133; }
    else if (b < 197) { layer = 3; local = b - 173; }
    else              { layer = 4; local = b - 197; }
    const int NTa[5]  = {6, 5, 4, 3, 2};
    const int FINa[5] = {203, 175, 150, 128, 80};
    const int FOa[5]  = {175, 150, 128, 80, 48};
    const float* Wp = (layer == 0) ? W1 : (layer == 1) ? W2 : (layer == 2) ? W3
                    : (layer == 3) ? W4 : W5;
    const int nt = NTa[layer], fin = FINa[layer], fout = FOa[layer];
    const int c = local / nt, t = local % nt;
    const int n  = t * 32 + (l & 31);
    const int kb = c * 16 + (l >> 5) * 8;
    uint hw[4], lw[4];
#pragma unroll
    for (int j = 0; j < 8; ++j) {
        int k = kb + j;
        float v = (n < fout && k < fin) ? Wp[(size_t)n * fin + k] : 0.0f;
        ushort hh = f2bf(v);
        ushort ll = f2bf(v - bf2f(hh));
        if (j & 1) { hw[j >> 1] |= ((uint)hh) << 16; lw[j >> 1] |= ((uint)ll) << 16; }
        else       { hw[j >> 1]  = hh;               lw[j >> 1]  = ll; }
    }
    char* dst = ws + (size_t)b * 2048 + l * 16;
    *(uint4*)dst          = make_uint4(hw[0], hw[1], hw[2], hw[3]);
    *(uint4*)(dst + 1024) = make_uint4(lw[0], lw[1], lw[2], lw[3]);
}

// ---------------- one layer: A from packed LDS plane, B direct from global ---
// MT=1: wave w owns tile t=w (waves with w >= NT idle through the K-loop).
// SR = stride of the A plane (XROW for layer 1, SROW for the rest).
template<int KC, int NT, int FOUT, int PADN, int SR, bool ACT, bool LAST>
__device__ __forceinline__ void run_layer(const char* __restrict__ wsL,
    const float* __restrict__ bias, const uint* aP, uint* oP, float* outg,
    int row0, int l, int w, int lx, int lh, int tid)
{
    f32x16 acc;
    {
        float bv = 0.0f;
        if (w < NT) { int n = w * 32 + lx; bv = (n < FOUT) ? bias[n] : 0.0f; }
#pragma unroll
        for (int r = 0; r < 16; ++r) acc[r] = bv;
    }

    if (w < NT) {   // wave-uniform branch
#pragma unroll
        for (int c = 0; c < KC; ++c) {
            const uint4* wp = (const uint4*)wsL + (size_t)((c * NT + w) * 2) * 64 + l;
            U4S8 bh, bl;
            bh.u = wp[0];      // hi plane (1024 B = 64 uint4)
            bl.u = wp[64];     // lo plane
            const uint* ap = aP + lx * SR + c * 16 + lh * 8;
            uint4 d0 = *(const uint4*)ap;          // ds_read_b128, 16B-aligned
            uint4 d1 = *(const uint4*)(ap + 4);
            uint dd[8] = {d0.x, d0.y, d0.z, d0.w, d1.x, d1.y, d1.z, d1.w};
            U4S8 ah, al;
            uint* aHu = (uint*)&ah; uint* aLu = (uint*)&al;
#pragma unroll
            for (int j = 0; j < 4; ++j) {
                aHu[j] = (dd[2*j] >> 16)     | (dd[2*j + 1] & 0xFFFF0000u);
                aLu[j] = (dd[2*j] & 0xFFFFu) | (dd[2*j + 1] << 16);
            }
            acc = __builtin_amdgcn_mfma_f32_32x32x16_bf16(ah.s, bh.s, acc, 0, 0, 0);
            acc = __builtin_amdgcn_mfma_f32_32x32x16_bf16(al.s, bh.s, acc, 0, 0, 0);
            acc = __builtin_amdgcn_mfma_f32_32x32x16_bf16(ah.s, bl.s, acc, 0, 0, 0);
        }
    }
    if (!LAST) __syncthreads();   // pre-D: all A-plane reads done before overwrite

    // D-phase: acc -> tanh -> packed oP (or global out)
    if (w < NT) {
#pragma unroll
        for (int r = 0; r < 16; ++r) {
            float vv = acc[r];
            if (ACT) vv = fast_tanh(vv);
            int rowl = (r & 3) + 8 * (r >> 2) + 4 * lh;
            int col  = w * 32 + lx;
            if (LAST) {
                if (col < 48) outg[(size_t)(row0 + rowl) * 48 + col] = vv;
            } else if (col < FOUT) {
                uint r1  = rbf(vv);
                uint hib = r1 & 0xFFFF0000u;
                float lo = vv - __uint_as_float(hib);
                uint r2  = rbf(lo);
                oP[rowl * SROW + col] = hib | (r2 >> 16);   // hi in high16, lo in low16
            }
        }
    }
    if (!LAST) {
        if (PADN > 0) {
            for (int idx = tid; idx < 32 * PADN; idx += NTHREADS) {
                int row = idx / PADN, p = idx % PADN;
                oP[row * SROW + FOUT + p] = 0u;
            }
        }
        __syncthreads();    // post-D: outputs visible to next layer
    }
}

__global__ __launch_bounds__(NTHREADS, 5)
void mlp_mfma(const float* __restrict__ x,
              const float* __restrict__ b1, const float* __restrict__ b2,
              const float* __restrict__ b3, const float* __restrict__ b4,
              const float* __restrict__ b5,
              const char* __restrict__ ws, float* __restrict__ out)
{
    // One union buffer: staged-x plane (32 x XROW, 27136 B) overlapped with
    // actP (32 x SROW, 23040 B). Safe: actP is first written in L1's D-phase,
    // after the pre-D barrier that ends all staged-x reads.
    __shared__ __align__(16) uint buf[32 * XROW];   // 27136 B

    const int tid = threadIdx.x;
    const int l = tid & 63, w = tid >> 6;
    const int lx = l & 31, lh = l >> 5;
    const int row0 = blockIdx.x * 32;

    // ---- stage + split x ONCE: packed hi|lo, cols 0..207 (203.. zero) ----
    for (int e = tid; e < 32 * 208; e += NTHREADS) {
        int row = e / 208, col = e - row * 208;
        float v = 0.0f;
        if (col < 203) v = x[(size_t)(row0 + row) * 203 + col];
        uint r1  = rbf(v);
        uint hib = r1 & 0xFFFF0000u;
        float lo = v - __uint_as_float(hib);
        uint r2  = rbf(lo);
        buf[row * XROW + col] = hib | (r2 >> 16);
    }
    __syncthreads();

    run_layer<13, 6, 175,  1, XROW, true,  false>(ws,             b1, buf, buf, nullptr, row0, l, w, lx, lh, tid);
    run_layer<11, 5, 150, 10, SROW, true,  false>(ws +  78 * 2048, b2, buf, buf, nullptr, row0, l, w, lx, lh, tid);
    run_layer<10, 4, 128,  0, SROW, true,  false>(ws + 133 * 2048, b3, buf, buf, nullptr, row0, l, w, lx, lh, tid);
    run_layer< 8, 3,  80,  0, SROW, true,  false>(ws + 173 * 2048, b4, buf, buf, nullptr, row0, l, w, lx, lh, tid);
    run_layer< 5, 2,  48,  0, SROW, false, true >(ws + 197 * 2048, b5, buf, buf, out,     row0, l, w, lx, lh, tid);
}

extern "C" void kernel_launch(void* const* d_in, const int* in_sizes, int n_in,
                              void* d_out, int out_size, void* d_ws, size_t ws_size,
                              hipStream_t stream) {
    (void)in_sizes; (void)n_in; (void)ws_size; (void)out_size;
    const float* x  = (const float*)d_in[0];
    const float* W1 = (const float*)d_in[1];
    const float* b1 = (const float*)d_in[2];
    const float* W2 = (const float*)d_in[3];
    const float* b2 = (const float*)d_in[4];
    const float* W3 = (const float*)d_in[5];
    const float* b3 = (const float*)d_in[6];
    const float* W4 = (const float*)d_in[7];
    const float* b4 = (const float*)d_in[8];
    const float* W5 = (const float*)d_in[9];
    const float* b5 = (const float*)d_in[10];
    float* out = (float*)d_out;
    char* ws = (char*)d_ws;      // needs 423936 B (fits; verified in R2)

    hipLaunchKernelGGL(prep_weights, dim3(207), dim3(64), 0, stream,
                       W1, W2, W3, W4, W5, ws);
    hipLaunchKernelGGL(mlp_mfma, dim3(131072 / 32), dim3(NTHREADS), 0, stream,
                       x, b1, b2, b3, b4, b5, ws, out);
}

// Round 4
// 311.922 us; speedup vs baseline: 8.1522x; 1.0479x over previous
//
#include <hip/hip_runtime.h>

// Fused 5-layer MLP 203->175->150->128->80->48, tanh on 1-4, B=131072, fp32 I/O.
// Split-bf16 MFMA (v = hi+lo bf16; 3 MFMAs aH*bH + aL*bH + aH*bL), 32x32x16.
// R7: kill the K-loop repack. Activations stored as TWO pre-split bf16 ushort
// planes aH[row][k], aL[row][k] in MFMA-A-fragment-ready layout: lane l
// ds_read_b128's 8 consecutive bf16 at row lx, k-off c*16+lh*8 -> fragment
// registers directly, ZERO unpack VALU (R6 spent ~16 VALU/chunk/wave on
// unpacking, replicated across all 6 waves reading the same rows -> VALU-bound
// K-loop, VALUBusy 53% / MfmaUtil 17%). Splitters (x-stage, d_phase) write two
// ds_write_b16 instead of one packed b32 (2-way same-dword aliasing = free).
// Plane stride 116 dwords == 20 mod 32 -> same proven conflict-free period-8
// b128 pattern as R3..R6. Layer 1 now structurally identical to layers 2-5.
// Register demand ~60-70 incl 16-AGPR acc -> (384,5) cap 102, no spill
// (R4/R5 lesson: VGPR_Count excludes AGPRs; cap must exceed arch+acc demand).
// LDS 29.7 KB. Numerics bit-identical to R3/R5/R6.

typedef short short8 __attribute__((ext_vector_type(8)));
typedef float f32x16 __attribute__((ext_vector_type(16)));
typedef unsigned int uint;
typedef unsigned short ushort;

#define PSTR 116       // plane stride in dwords: mod 32 = 20 -> period-8 full-bank b128
#define PSTRU (PSTR*2) // plane stride in ushorts
#define NTHREADS 384

__device__ __forceinline__ ushort f2bf(float f) {
    uint u = __float_as_uint(f);
    u += 0x7FFFu + ((u >> 16) & 1u);
    return (ushort)(u >> 16);
}
__device__ __forceinline__ float bf2f(ushort h) { return __uint_as_float(((uint)h) << 16); }
__device__ __forceinline__ float fast_tanh(float x) {
    float e = __expf(2.0f * x);
    return 1.0f - 2.0f / (e + 1.0f);
}
__device__ __forceinline__ uint rbf(float v) {   // bf16-RNE rounded bits; hi16 = result>>16
    uint u = __float_as_uint(v);
    return u + 0x7FFFu + ((u >> 16) & 1u);
}

union U4S8 { uint4 u; short8 s; };

// ---------------- prep: split weights into ws in B-fragment order ------------
// (unchanged — verified correct.) Tile pair p = c*NT + t: 2048 B =
// [hi plane 1024B][lo plane 1024B], lane l holds B[k=(l>>5)*8+j][n=l&31].
__global__ void prep_weights(const float* __restrict__ W1, const float* __restrict__ W2,
                             const float* __restrict__ W3, const float* __restrict__ W4,
                             const float* __restrict__ W5, char* __restrict__ ws)
{
    const int b = blockIdx.x, l = threadIdx.x;   // 207 blocks x 64 threads
    int layer, local;
    if      (b <  78) { layer = 0; local = b; }
    else if (b < 133) { layer = 1; local = b - 78; }
    else if (b < 173) { layer = 2; local = b - 133; }
    else if (b < 197) { layer = 3; local = b - 173; }
    else              { layer = 4; local = b - 197; }
    const int NTa[5]  = {6, 5, 4, 3, 2};
    const int FINa[5] = {203, 175, 150, 128, 80};
    const int FOa[5]  = {175, 150, 128, 80, 48};
    const float* Wp = (layer == 0) ? W1 : (layer == 1) ? W2 : (layer == 2) ? W3
                    : (layer == 3) ? W4 : W5;
    const int nt = NTa[layer], fin = FINa[layer], fout = FOa[layer];
    const int c = local / nt, t = local % nt;
    const int n  = t * 32 + (l & 31);
    const int kb = c * 16 + (l >> 5) * 8;
    uint hw[4], lw[4];
#pragma unroll
    for (int j = 0; j < 8; ++j) {
        int k = kb + j;
        float v = (n < fout && k < fin) ? Wp[(size_t)n * fin + k] : 0.0f;
        ushort hh = f2bf(v);
        ushort ll = f2bf(v - bf2f(hh));
        if (j & 1) { hw[j >> 1] |= ((uint)hh) << 16; lw[j >> 1] |= ((uint)ll) << 16; }
        else       { hw[j >> 1]  = hh;               lw[j >> 1]  = ll; }
    }
    char* dst = ws + (size_t)b * 2048 + l * 16;
    *(uint4*)dst          = make_uint4(hw[0], hw[1], hw[2], hw[3]);
    *(uint4*)(dst + 1024) = make_uint4(lw[0], lw[1], lw[2], lw[3]);
}

// ---------------- one layer: A frags ds_read_b128 direct, B from global ------
// MT=1: wave w owns tile t=w (waves w >= NT idle through the K-loop).
template<int KC, int NT, int FOUT, int PADN, bool ACT, bool LAST>
__device__ __forceinline__ void run_layer(const char* __restrict__ wsL,
    const float* __restrict__ bias, uint* aH, uint* aL, float* outg,
    int row0, int l, int w, int lx, int lh, int tid)
{
    f32x16 acc;
    {
        float bv = 0.0f;
        if (w < NT) { int n = w * 32 + lx; bv = (n < FOUT) ? bias[n] : 0.0f; }
#pragma unroll
        for (int r = 0; r < 16; ++r) acc[r] = bv;
    }

    if (w < NT) {   // wave-uniform branch
        const char* ha = (const char*)aH + lx * (PSTR * 4) + lh * 16;
        const char* la = (const char*)aL + lx * (PSTR * 4) + lh * 16;
#pragma unroll
        for (int c = 0; c < KC; ++c) {
            const uint4* wp = (const uint4*)wsL + (size_t)((c * NT + w) * 2) * 64 + l;
            U4S8 bh, bl, ah, al;
            bh.u = wp[0];                               // hi plane (1024 B)
            bl.u = wp[64];                              // lo plane
            ah.u = *(const uint4*)(ha + c * 32);        // ds_read_b128, frag-ready
            al.u = *(const uint4*)(la + c * 32);
            acc = __builtin_amdgcn_mfma_f32_32x32x16_bf16(ah.s, bh.s, acc, 0, 0, 0);
            acc = __builtin_amdgcn_mfma_f32_32x32x16_bf16(al.s, bh.s, acc, 0, 0, 0);
            acc = __builtin_amdgcn_mfma_f32_32x32x16_bf16(ah.s, bl.s, acc, 0, 0, 0);
        }
    }
    if (!LAST) __syncthreads();   // pre-D: all plane reads done before overwrite

    // D-phase: acc -> tanh -> split hi/lo -> planes (or global out)
    if (w < NT) {
        ushort* pH = (ushort*)aH;
        ushort* pL = (ushort*)aL;
#pragma unroll
        for (int r = 0; r < 16; ++r) {
            float vv = acc[r];
            if (ACT) vv = fast_tanh(vv);
            int rowl = (r & 3) + 8 * (r >> 2) + 4 * lh;
            int col  = w * 32 + lx;
            if (LAST) {
                if (col < 48) outg[(size_t)(row0 + rowl) * 48 + col] = vv;
            } else if (col < FOUT) {
                uint r1  = rbf(vv);
                uint hib = r1 & 0xFFFF0000u;
                float lo = vv - __uint_as_float(hib);
                uint r2  = rbf(lo);
                pH[rowl * PSTRU + col] = (ushort)(r1 >> 16);
                pL[rowl * PSTRU + col] = (ushort)(r2 >> 16);
            }
        }
    }
    if (!LAST) {
        if (PADN > 0) {
            ushort* pH = (ushort*)aH;
            ushort* pL = (ushort*)aL;
            for (int idx = tid; idx < 32 * PADN; idx += NTHREADS) {
                int row = idx / PADN, p = idx % PADN;
                pH[row * PSTRU + FOUT + p] = 0;
                pL[row * PSTRU + FOUT + p] = 0;
            }
        }
        __syncthreads();    // post-D: outputs visible to next layer
    }
}

__global__ __launch_bounds__(NTHREADS, 5)
void mlp_mfma(const float* __restrict__ x,
              const float* __restrict__ b1, const float* __restrict__ b2,
              const float* __restrict__ b3, const float* __restrict__ b4,
              const float* __restrict__ b5,
              const char* __restrict__ ws, float* __restrict__ out)
{
    __shared__ __align__(16) uint aH[32 * PSTR];   // 14848 B — bf16 hi plane
    __shared__ __align__(16) uint aL[32 * PSTR];   // 14848 B — bf16 lo plane

    const int tid = threadIdx.x;
    const int l = tid & 63, w = tid >> 6;
    const int lx = l & 31, lh = l >> 5;
    const int row0 = blockIdx.x * 32;

    // ---- stage + split x ONCE into the two planes (cols 203..207 zero) ----
    {
        ushort* pH = (ushort*)aH;
        ushort* pL = (ushort*)aL;
        for (int e = tid; e < 32 * 208; e += NTHREADS) {
            int row = e / 208, col = e - row * 208;
            float v = (col < 203) ? x[(size_t)(row0 + row) * 203 + col] : 0.0f;
            uint r1  = rbf(v);
            uint hib = r1 & 0xFFFF0000u;
            float lo = v - __uint_as_float(hib);
            uint r2  = rbf(lo);
            pH[row * PSTRU + col] = (ushort)(r1 >> 16);
            pL[row * PSTRU + col] = (ushort)(r2 >> 16);
        }
    }
    __syncthreads();

    run_layer<13, 6, 175,  1, true,  false>(ws,              b1, aH, aL, nullptr, row0, l, w, lx, lh, tid);
    run_layer<11, 5, 150, 10, true,  false>(ws +  78 * 2048, b2, aH, aL, nullptr, row0, l, w, lx, lh, tid);
    run_layer<10, 4, 128,  0, true,  false>(ws + 133 * 2048, b3, aH, aL, nullptr, row0, l, w, lx, lh, tid);
    run_layer< 8, 3,  80,  0, true,  false>(ws + 173 * 2048, b4, aH, aL, nullptr, row0, l, w, lx, lh, tid);
    run_layer< 5, 2,  48,  0, false, true >(ws + 197 * 2048, b5, aH, aL, out,     row0, l, w, lx, lh, tid);
}

extern "C" void kernel_launch(void* const* d_in, const int* in_sizes, int n_in,
                              void* d_out, int out_size, void* d_ws, size_t ws_size,
                              hipStream_t stream) {
    (void)in_sizes; (void)n_in; (void)ws_size; (void)out_size;
    const float* x  = (const float*)d_in[0];
    const float* W1 = (const float*)d_in[1];
    const float* b1 = (const float*)d_in[2];
    const float* W2 = (const float*)d_in[3];
    const float* b2 = (const float*)d_in[4];
    const float* W3 = (const float*)d_in[5];
    const float* b3 = (const float*)d_in[6];
    const float* W4 = (const float*)d_in[7];
    const float* b4 = (const float*)d_in[8];
    const float* W5 = (const float*)d_in[9];
    const float* b5 = (const float*)d_in[10];
    float* out = (float*)d_out;
    char* ws = (char*)d_ws;      // needs 423936 B (fits; verified in R2)

    hipLaunchKernelGGL(prep_weights, dim3(207), dim3(64), 0, stream,
                       W1, W2, W3, W4, W5, ws);
    hipLaunchKernelGGL(mlp_mfma, dim3(131072 / 32), dim3(NTHREADS), 0, stream,
                       x, b1, b2, b3, b4, b5, ws, out);
}

// Round 6
// 280.920 us; speedup vs baseline: 9.0519x; 1.1104x over previous
//
#include <hip/hip_runtime.h>

// Fused 5-layer MLP 203->175->150->128->80->48, tanh on 1-4, B=131072, fp32 I/O.
// Split-bf16 MFMA (v = hi+lo bf16; 3 MFMAs aH*bH + aL*bH + aH*bL), 32x32x16.
// R8 (resubmit — previous round was an infra failure, no kernel signal):
// VALU-issue + latency fixes on the proven R7 structure (384 thr, 6 waves,
// MT=1, M=32, two pre-split bf16 planes, stride 116 ==20 mod 32 conflict-free).
//  - tanh: f32 division (10 inst, no fast-math) -> v_rcp + fma (rcp <=1ulp;
//    perturbation 2^-22 << split error 2^-17; absmax unchanged).
//  - splits: manual rbf (8 inst/elem) -> v_cvt_pk_bf16_f32 (HW RNE, bit-
//    identical), pairs: stage writes packed b32; d_phase pairs hit adjacent
//    rows (b16 + b16_d16_hi).
//  - K-loop: explicit 1-chunk software pipeline (even/odd named regs; chunk
//    c+1's 2 global b128 + 2 ds_read b128 issued before chunk c's MFMAs).
//    R7's VGPR_Count=32 proved the compiler held only 1 chunk in flight ->
//    exposed ~200cy L2 latency per chunk. +32 VGPR, ~70 total < cap 102.
//  - R4/R5 lesson kept: cap (384,5)=102 comfortably above demand; watch
//    WRITE_SIZE==24.5MB as the no-spill check.

typedef short short8 __attribute__((ext_vector_type(8)));
typedef float f32x16 __attribute__((ext_vector_type(16)));
typedef unsigned int uint;
typedef unsigned short ushort;

#define PSTR 116       // plane stride in dwords: mod 32 = 20 -> period-8 full-bank b128
#define PSTRU (PSTR*2) // plane stride in ushorts
#define NTHREADS 384

__device__ __forceinline__ ushort f2bf(float f) {
    uint u = __float_as_uint(f);
    u += 0x7FFFu + ((u >> 16) & 1u);
    return (ushort)(u >> 16);
}
__device__ __forceinline__ float bf2f(ushort h) { return __uint_as_float(((uint)h) << 16); }
__device__ __forceinline__ float fast_tanh(float x) {
    float e = __expf(2.0f * x);                      // v_mul + v_mul(log2e) + v_exp
    float t = __builtin_amdgcn_rcpf(e + 1.0f);       // v_add + v_rcp
    return fmaf(-2.0f, t, 1.0f);                     // v_fma
}
// D.lo16 = bf16_rne(s0), D.hi16 = bf16_rne(s1) — bit-identical to rbf's RNE.
__device__ __forceinline__ uint cvt_pk_bf16(float s0, float s1) {
    uint r;
    asm("v_cvt_pk_bf16_f32 %0, %1, %2" : "=v"(r) : "v"(s0), "v"(s1));
    return r;
}

union U4S8 { uint4 u; short8 s; };

// ---------------- prep: split weights into ws in B-fragment order ------------
// (unchanged — verified correct.) Tile pair p = c*NT + t: 2048 B =
// [hi plane 1024B][lo plane 1024B], lane l holds B[k=(l>>5)*8+j][n=l&31].
__global__ void prep_weights(const float* __restrict__ W1, const float* __restrict__ W2,
                             const float* __restrict__ W3, const float* __restrict__ W4,
                             const float* __restrict__ W5, char* __restrict__ ws)
{
    const int b = blockIdx.x, l = threadIdx.x;   // 207 blocks x 64 threads
    int layer, local;
    if      (b <  78) { layer = 0; local = b; }
    else if (b < 133) { layer = 1; local = b - 78; }
    else if (b < 173) { layer = 2; local = b - 133; }
    else if (b < 197) { layer = 3; local = b - 173; }
    else              { layer = 4; local = b - 197; }
    const int NTa[5]  = {6, 5, 4, 3, 2};
    const int FINa[5] = {203, 175, 150, 128, 80};
    const int FOa[5]  = {175, 150, 128, 80, 48};
    const float* Wp = (layer == 0) ? W1 : (layer == 1) ? W2 : (layer == 2) ? W3
                    : (layer == 3) ? W4 : W5;
    const int nt = NTa[layer], fin = FINa[layer], fout = FOa[layer];
    const int c = local / nt, t = local % nt;
    const int n  = t * 32 + (l & 31);
    const int kb = c * 16 + (l >> 5) * 8;
    uint hw[4], lw[4];
#pragma unroll
    for (int j = 0; j < 8; ++j) {
        int k = kb + j;
        float v = (n < fout && k < fin) ? Wp[(size_t)n * fin + k] : 0.0f;
        ushort hh = f2bf(v);
        ushort ll = f2bf(v - bf2f(hh));
        if (j & 1) { hw[j >> 1] |= ((uint)hh) << 16; lw[j >> 1] |= ((uint)ll) << 16; }
        else       { hw[j >> 1]  = hh;               lw[j >> 1]  = ll; }
    }
    char* dst = ws + (size_t)b * 2048 + l * 16;
    *(uint4*)dst          = make_uint4(hw[0], hw[1], hw[2], hw[3]);
    *(uint4*)(dst + 1024) = make_uint4(lw[0], lw[1], lw[2], lw[3]);
}

// ---------------- one layer: pipelined K-loop, A frags b128, B from global ---
// MT=1: wave w owns tile t=w (waves w >= NT idle through the K-loop).
template<int KC, int NT, int FOUT, int PADN, bool ACT, bool LAST>
__device__ __forceinline__ void run_layer(const char* __restrict__ wsL,
    const float* __restrict__ bias, uint* aH, uint* aL, float* outg,
    int row0, int l, int w, int lx, int lh, int tid)
{
    f32x16 acc;
    {
        float bv = 0.0f;
        if (w < NT) { int n = w * 32 + lx; bv = (n < FOUT) ? bias[n] : 0.0f; }
#pragma unroll
        for (int r = 0; r < 16; ++r) acc[r] = bv;
    }

    if (w < NT) {   // wave-uniform branch
        const char* ha = (const char*)aH + lx * (PSTR * 4) + lh * 16;
        const char* la = (const char*)aL + lx * (PSTR * 4) + lh * 16;
        const uint4* wsb = (const uint4*)wsL + (size_t)(w * 2) * 64 + l;

        U4S8 bhA, blA, ahA, alA, bhB, blB, ahB, alB;
        bhA.u = wsb[0];                         // chunk 0 weights (hi/lo planes)
        blA.u = wsb[64];
        ahA.u = *(const uint4*)(ha);            // chunk 0 A frags
        alA.u = *(const uint4*)(la);

#pragma unroll
        for (int c = 0; c < KC; ++c) {
            const bool ev = ((c & 1) == 0);
            U4S8& bh = ev ? bhA : bhB;  U4S8& bl = ev ? blA : blB;
            U4S8& ah = ev ? ahA : ahB;  U4S8& al = ev ? alA : alB;
            if (c + 1 < KC) {           // prefetch chunk c+1 before MFMAs of c
                U4S8& nbh = ev ? bhB : bhA;  U4S8& nbl = ev ? blB : blA;
                U4S8& nah = ev ? ahB : ahA;  U4S8& nal = ev ? alB : alA;
                const uint4* wpn = wsb + (size_t)((c + 1) * NT * 2) * 64;
                nbh.u = wpn[0];
                nbl.u = wpn[64];
                nah.u = *(const uint4*)(ha + (c + 1) * 32);
                nal.u = *(const uint4*)(la + (c + 1) * 32);
            }
            acc = __builtin_amdgcn_mfma_f32_32x32x16_bf16(ah.s, bh.s, acc, 0, 0, 0);
            acc = __builtin_amdgcn_mfma_f32_32x32x16_bf16(al.s, bh.s, acc, 0, 0, 0);
            acc = __builtin_amdgcn_mfma_f32_32x32x16_bf16(ah.s, bl.s, acc, 0, 0, 0);
        }
    }
    if (!LAST) __syncthreads();   // pre-D: all plane reads done before overwrite

    // D-phase: acc -> tanh -> cvt_pk split -> planes (or global out).
    // Pairs (2i, 2i+1) land on adjacent rows rowl, rowl+1.
    if (w < NT) {
        ushort* pH = (ushort*)aH;
        ushort* pL = (ushort*)aL;
        const int col = w * 32 + lx;
#pragma unroll
        for (int i = 0; i < 8; ++i) {
            float v0 = acc[2 * i], v1 = acc[2 * i + 1];
            if (ACT) { v0 = fast_tanh(v0); v1 = fast_tanh(v1); }
            const int r0 = 2 * i;
            const int rowl = (r0 & 3) + 8 * (r0 >> 2) + 4 * lh;
            if (LAST) {
                if (col < 48) {
                    outg[(size_t)(row0 + rowl) * 48 + col]     = v0;
                    outg[(size_t)(row0 + rowl + 1) * 48 + col] = v1;
                }
            } else if (col < FOUT) {
                uint chi = cvt_pk_bf16(v0, v1);
                float h0 = __uint_as_float(chi << 16);
                float h1 = __uint_as_float(chi & 0xFFFF0000u);
                uint clo = cvt_pk_bf16(v0 - h0, v1 - h1);
                pH[rowl * PSTRU + col]       = (ushort)chi;
                pH[(rowl + 1) * PSTRU + col] = (ushort)(chi >> 16);   // d16_hi
                pL[rowl * PSTRU + col]       = (ushort)clo;
                pL[(rowl + 1) * PSTRU + col] = (ushort)(clo >> 16);
            }
        }
    }
    if (!LAST) {
        if (PADN > 0) {
            ushort* pH = (ushort*)aH;
            ushort* pL = (ushort*)aL;
            for (int idx = tid; idx < 32 * PADN; idx += NTHREADS) {
                int row = idx / PADN, p = idx % PADN;
                pH[row * PSTRU + FOUT + p] = 0;
                pL[row * PSTRU + FOUT + p] = 0;
            }
        }
        __syncthreads();    // post-D: outputs visible to next layer
    }
}

__global__ __launch_bounds__(NTHREADS, 5)
void mlp_mfma(const float* __restrict__ x,
              const float* __restrict__ b1, const float* __restrict__ b2,
              const float* __restrict__ b3, const float* __restrict__ b4,
              const float* __restrict__ b5,
              const char* __restrict__ ws, float* __restrict__ out)
{
    __shared__ __align__(16) uint aH[32 * PSTR];   // 14848 B — bf16 hi plane
    __shared__ __align__(16) uint aL[32 * PSTR];   // 14848 B — bf16 lo plane

    const int tid = threadIdx.x;
    const int l = tid & 63, w = tid >> 6;
    const int lx = l & 31, lh = l >> 5;
    const int row0 = blockIdx.x * 32;

    // ---- stage + split x ONCE, pair-wise (dword cols; 203..207 zero) ----
    for (int e = tid; e < 32 * 104; e += NTHREADS) {
        int row = e / 104, dcol = e - row * 104;
        int col = dcol * 2;
        const float* xp = x + (size_t)(row0 + row) * 203;
        float v0 = (col < 203) ? xp[col] : 0.0f;
        float v1 = (col + 1 < 203) ? xp[col + 1] : 0.0f;
        uint chi = cvt_pk_bf16(v0, v1);
        float h0 = __uint_as_float(chi << 16);
        float h1 = __uint_as_float(chi & 0xFFFF0000u);
        uint clo = cvt_pk_bf16(v0 - h0, v1 - h1);
        aH[row * PSTR + dcol] = chi;
        aL[row * PSTR + dcol] = clo;
    }
    __syncthreads();

    run_layer<13, 6, 175,  1, true,  false>(ws,              b1, aH, aL, nullptr, row0, l, w, lx, lh, tid);
    run_layer<11, 5, 150, 10, true,  false>(ws +  78 * 2048, b2, aH, aL, nullptr, row0, l, w, lx, lh, tid);
    run_layer<10, 4, 128,  0, true,  false>(ws + 133 * 2048, b3, aH, aL, nullptr, row0, l, w, lx, lh, tid);
    run_layer< 8, 3,  80,  0, true,  false>(ws + 173 * 2048, b4, aH, aL, nullptr, row0, l, w, lx, lh, tid);
    run_layer< 5, 2,  48,  0, false, true >(ws + 197 * 2048, b5, aH, aL, out,     row0, l, w, lx, lh, tid);
}

extern "C" void kernel_launch(void* const* d_in, const int* in_sizes, int n_in,
                              void* d_out, int out_size, void* d_ws, size_t ws_size,
                              hipStream_t stream) {
    (void)in_sizes; (void)n_in; (void)ws_size; (void)out_size;
    const float* x  = (const float*)d_in[0];
    const float* W1 = (const float*)d_in[1];
    const float* b1 = (const float*)d_in[2];
    const float* W2 = (const float*)d_in[3];
    const float* b2 = (const float*)d_in[4];
    const float* W3 = (const float*)d_in[5];
    const float* b3 = (const float*)d_in[6];
    const float* W4 = (const float*)d_in[7];
    const float* b4 = (const float*)d_in[8];
    const float* W5 = (const float*)d_in[9];
    const float* b5 = (const float*)d_in[10];
    float* out = (float*)d_out;
    char* ws = (char*)d_ws;      // needs 423936 B (fits; verified in R2)

    hipLaunchKernelGGL(prep_weights, dim3(207), dim3(64), 0, stream,
                       W1, W2, W3, W4, W5, ws);
    hipLaunchKernelGGL(mlp_mfma, dim3(131072 / 32), dim3(NTHREADS), 0, stream,
                       x, b1, b2, b3, b4, b5, ws, out);
}

// Round 7
// 279.075 us; speedup vs baseline: 9.1117x; 1.0066x over previous
//
#include <hip/hip_runtime.h>

// Fused 5-layer MLP 203->175->150->128->80->48, tanh on 1-4, B=131072, fp32 I/O.
// Split-bf16 MFMA (v = hi+lo bf16; 3 MFMAs aH*bH + aL*bH + aH*bL), 32x32x16.
// R9: halve the L2 weight stream + raise occupancy. R8 accounting: VALU 48us,
// MFMA 33us (==pipe demand), DS 25us, L2 weights 4096 blk x 414KB = 1.74GB /
// 34.5TB/s = 50us <- unmodeled floor. Fix: M=64/block, 12 waves (768 thr),
// grid 2048. Wave w -> row-group rg=w/6, N-tile t=w%6; waves (w, w+6) load the
// SAME weight fragment concurrently -> 2nd hits L1 (24KB/chunk < 32KB L1) ->
// L2 stream ~25us. Half the blocks -> half the total barrier serialization.
// LDS 59.4KB -> exactly 2 blocks/CU = 24 waves (75% occ, was 57%). Inner loop
// byte-identical to R8 (demand ~48 regs incl AGPR); launch_bounds(768,4) cap
// 128 -> no spill (R4/R5 lesson; watch WRITE_SIZE==24.5MB).

typedef short short8 __attribute__((ext_vector_type(8)));
typedef float f32x16 __attribute__((ext_vector_type(16)));
typedef unsigned int uint;
typedef unsigned short ushort;

#define PSTR 116       // plane stride in dwords: mod 32 = 20 -> period-8 full-bank b128
#define PSTRU (PSTR*2) // plane stride in ushorts
#define NTHREADS 768
#define MROWS 64

__device__ __forceinline__ ushort f2bf(float f) {
    uint u = __float_as_uint(f);
    u += 0x7FFFu + ((u >> 16) & 1u);
    return (ushort)(u >> 16);
}
__device__ __forceinline__ float bf2f(ushort h) { return __uint_as_float(((uint)h) << 16); }
__device__ __forceinline__ float fast_tanh(float x) {
    float e = __expf(2.0f * x);                      // v_mul + v_mul(log2e) + v_exp
    float t = __builtin_amdgcn_rcpf(e + 1.0f);       // v_add + v_rcp
    return fmaf(-2.0f, t, 1.0f);                     // v_fma
}
// D.lo16 = bf16_rne(s0), D.hi16 = bf16_rne(s1) — bit-identical to rbf's RNE.
__device__ __forceinline__ uint cvt_pk_bf16(float s0, float s1) {
    uint r;
    asm("v_cvt_pk_bf16_f32 %0, %1, %2" : "=v"(r) : "v"(s0), "v"(s1));
    return r;
}

union U4S8 { uint4 u; short8 s; };

// ---------------- prep: split weights into ws in B-fragment order ------------
// (unchanged — verified correct.) Tile pair p = c*NT + t: 2048 B =
// [hi plane 1024B][lo plane 1024B], lane l holds B[k=(l>>5)*8+j][n=l&31].
__global__ void prep_weights(const float* __restrict__ W1, const float* __restrict__ W2,
                             const float* __restrict__ W3, const float* __restrict__ W4,
                             const float* __restrict__ W5, char* __restrict__ ws)
{
    const int b = blockIdx.x, l = threadIdx.x;   // 207 blocks x 64 threads
    int layer, local;
    if      (b <  78) { layer = 0; local = b; }
    else if (b < 133) { layer = 1; local = b - 78; }
    else if (b < 173) { layer = 2; local = b - 133; }
    else if (b < 197) { layer = 3; local = b - 173; }
    else              { layer = 4; local = b - 197; }
    const int NTa[5]  = {6, 5, 4, 3, 2};
    const int FINa[5] = {203, 175, 150, 128, 80};
    const int FOa[5]  = {175, 150, 128, 80, 48};
    const float* Wp = (layer == 0) ? W1 : (layer == 1) ? W2 : (layer == 2) ? W3
                    : (layer == 3) ? W4 : W5;
    const int nt = NTa[layer], fin = FINa[layer], fout = FOa[layer];
    const int c = local / nt, t = local % nt;
    const int n  = t * 32 + (l & 31);
    const int kb = c * 16 + (l >> 5) * 8;
    uint hw[4], lw[4];
#pragma unroll
    for (int j = 0; j < 8; ++j) {
        int k = kb + j;
        float v = (n < fout && k < fin) ? Wp[(size_t)n * fin + k] : 0.0f;
        ushort hh = f2bf(v);
        ushort ll = f2bf(v - bf2f(hh));
        if (j & 1) { hw[j >> 1] |= ((uint)hh) << 16; lw[j >> 1] |= ((uint)ll) << 16; }
        else       { hw[j >> 1]  = hh;               lw[j >> 1]  = ll; }
    }
    char* dst = ws + (size_t)b * 2048 + l * 16;
    *(uint4*)dst          = make_uint4(hw[0], hw[1], hw[2], hw[3]);
    *(uint4*)(dst + 1024) = make_uint4(lw[0], lw[1], lw[2], lw[3]);
}

// ---------------- one layer: pipelined K-loop, A frags b128, B from global ---
// Wave w: row-group rg = w/6 (0 or 1), N-tile t = w%6; active iff t < NT.
// Paired waves (rg=0, rg=1) load identical weight fragments -> L1 reuse.
template<int KC, int NT, int FOUT, int PADN, bool ACT, bool LAST>
__device__ __forceinline__ void run_layer(const char* __restrict__ wsL,
    const float* __restrict__ bias, uint* aH, uint* aL, float* outg,
    int row0, int l, int rg, int t, int lx, int lh, int tid)
{
    f32x16 acc;
    {
        float bv = 0.0f;
        if (t < NT) { int n = t * 32 + lx; bv = (n < FOUT) ? bias[n] : 0.0f; }
#pragma unroll
        for (int r = 0; r < 16; ++r) acc[r] = bv;
    }

    if (t < NT) {   // wave-uniform branch
        const char* ha = (const char*)aH + (rg * 32 + lx) * (PSTR * 4) + lh * 16;
        const char* la = (const char*)aL + (rg * 32 + lx) * (PSTR * 4) + lh * 16;
        const uint4* wsb = (const uint4*)wsL + (size_t)(t * 2) * 64 + l;

        U4S8 bhA, blA, ahA, alA, bhB, blB, ahB, alB;
        bhA.u = wsb[0];                         // chunk 0 weights (hi/lo planes)
        blA.u = wsb[64];
        ahA.u = *(const uint4*)(ha);            // chunk 0 A frags
        alA.u = *(const uint4*)(la);

#pragma unroll
        for (int c = 0; c < KC; ++c) {
            const bool ev = ((c & 1) == 0);
            U4S8& bh = ev ? bhA : bhB;  U4S8& bl = ev ? blA : blB;
            U4S8& ah = ev ? ahA : ahB;  U4S8& al = ev ? alA : alB;
            if (c + 1 < KC) {           // prefetch chunk c+1 before MFMAs of c
                U4S8& nbh = ev ? bhB : bhA;  U4S8& nbl = ev ? blB : blA;
                U4S8& nah = ev ? ahB : ahA;  U4S8& nal = ev ? alB : alA;
                const uint4* wpn = wsb + (size_t)((c + 1) * NT * 2) * 64;
                nbh.u = wpn[0];
                nbl.u = wpn[64];
                nah.u = *(const uint4*)(ha + (c + 1) * 32);
                nal.u = *(const uint4*)(la + (c + 1) * 32);
            }
            acc = __builtin_amdgcn_mfma_f32_32x32x16_bf16(ah.s, bh.s, acc, 0, 0, 0);
            acc = __builtin_amdgcn_mfma_f32_32x32x16_bf16(al.s, bh.s, acc, 0, 0, 0);
            acc = __builtin_amdgcn_mfma_f32_32x32x16_bf16(ah.s, bl.s, acc, 0, 0, 0);
        }
    }
    if (!LAST) __syncthreads();   // pre-D: all plane reads done before overwrite

    // D-phase: acc -> tanh -> cvt_pk split -> planes (or global out).
    // Pairs (2i, 2i+1) land on adjacent rows rowl, rowl+1 (within rg's half).
    if (t < NT) {
        ushort* pH = (ushort*)aH;
        ushort* pL = (ushort*)aL;
        const int col = t * 32 + lx;
        const int rbase = rg * 32;
#pragma unroll
        for (int i = 0; i < 8; ++i) {
            float v0 = acc[2 * i], v1 = acc[2 * i + 1];
            if (ACT) { v0 = fast_tanh(v0); v1 = fast_tanh(v1); }
            const int r0 = 2 * i;
            const int rowl = rbase + (r0 & 3) + 8 * (r0 >> 2) + 4 * lh;
            if (LAST) {
                if (col < 48) {
                    outg[(size_t)(row0 + rowl) * 48 + col]     = v0;
                    outg[(size_t)(row0 + rowl + 1) * 48 + col] = v1;
                }
            } else if (col < FOUT) {
                uint chi = cvt_pk_bf16(v0, v1);
                float h0 = __uint_as_float(chi << 16);
                float h1 = __uint_as_float(chi & 0xFFFF0000u);
                uint clo = cvt_pk_bf16(v0 - h0, v1 - h1);
                pH[rowl * PSTRU + col]       = (ushort)chi;
                pH[(rowl + 1) * PSTRU + col] = (ushort)(chi >> 16);   // d16_hi
                pL[rowl * PSTRU + col]       = (ushort)clo;
                pL[(rowl + 1) * PSTRU + col] = (ushort)(clo >> 16);
            }
        }
    }
    if (!LAST) {
        if (PADN > 0) {
            ushort* pH = (ushort*)aH;
            ushort* pL = (ushort*)aL;
            for (int idx = tid; idx < MROWS * PADN; idx += NTHREADS) {
                int row = idx / PADN, p = idx % PADN;
                pH[row * PSTRU + FOUT + p] = 0;
                pL[row * PSTRU + FOUT + p] = 0;
            }
        }
        __syncthreads();    // post-D: outputs visible to next layer
    }
}

__global__ __launch_bounds__(NTHREADS, 4)
void mlp_mfma(const float* __restrict__ x,
              const float* __restrict__ b1, const float* __restrict__ b2,
              const float* __restrict__ b3, const float* __restrict__ b4,
              const float* __restrict__ b5,
              const char* __restrict__ ws, float* __restrict__ out)
{
    __shared__ __align__(16) uint aH[MROWS * PSTR];   // 29696 B — bf16 hi plane
    __shared__ __align__(16) uint aL[MROWS * PSTR];   // 29696 B — bf16 lo plane
    // total 59392 B -> exactly 2 blocks/CU (LDS-limited by design)

    const int tid = threadIdx.x;
    const int l = tid & 63, w = tid >> 6;             // 12 waves
    const int rg = w / 6, t = w - 6 * rg;             // row-group, N-tile
    const int lx = l & 31, lh = l >> 5;
    const int row0 = blockIdx.x * MROWS;

    // ---- stage + split x ONCE, pair-wise (dword cols; 203..207 zero) ----
    for (int e = tid; e < MROWS * 104; e += NTHREADS) {
        int row = e / 104, dcol = e - row * 104;
        int col = dcol * 2;
        const float* xp = x + (size_t)(row0 + row) * 203;
        float v0 = (col < 203) ? xp[col] : 0.0f;
        float v1 = (col + 1 < 203) ? xp[col + 1] : 0.0f;
        uint chi = cvt_pk_bf16(v0, v1);
        float h0 = __uint_as_float(chi << 16);
        float h1 = __uint_as_float(chi & 0xFFFF0000u);
        uint clo = cvt_pk_bf16(v0 - h0, v1 - h1);
        aH[row * PSTR + dcol] = chi;
        aL[row * PSTR + dcol] = clo;
    }
    __syncthreads();

    run_layer<13, 6, 175,  1, true,  false>(ws,              b1, aH, aL, nullptr, row0, l, rg, t, lx, lh, tid);
    run_layer<11, 5, 150, 10, true,  false>(ws +  78 * 2048, b2, aH, aL, nullptr, row0, l, rg, t, lx, lh, tid);
    run_layer<10, 4, 128,  0, true,  false>(ws + 133 * 2048, b3, aH, aL, nullptr, row0, l, rg, t, lx, lh, tid);
    run_layer< 8, 3,  80,  0, true,  false>(ws + 173 * 2048, b4, aH, aL, nullptr, row0, l, rg, t, lx, lh, tid);
    run_layer< 5, 2,  48,  0, false, true >(ws + 197 * 2048, b5, aH, aL, out,     row0, l, rg, t, lx, lh, tid);
}

extern "C" void kernel_launch(void* const* d_in, const int* in_sizes, int n_in,
                              void* d_out, int out_size, void* d_ws, size_t ws_size,
                              hipStream_t stream) {
    (void)in_sizes; (void)n_in; (void)ws_size; (void)out_size;
    const float* x  = (const float*)d_in[0];
    const float* W1 = (const float*)d_in[1];
    const float* b1 = (const float*)d_in[2];
    const float* W2 = (const float*)d_in[3];
    const float* b2 = (const float*)d_in[4];
    const float* W3 = (const float*)d_in[5];
    const float* b3 = (const float*)d_in[6];
    const float* W4 = (const float*)d_in[7];
    const float* b4 = (const float*)d_in[8];
    const float* W5 = (const float*)d_in[9];
    const float* b5 = (const float*)d_in[10];
    float* out = (float*)d_out;
    char* ws = (char*)d_ws;      // needs 423936 B (fits; verified in R2)

    hipLaunchKernelGGL(prep_weights, dim3(207), dim3(64), 0, stream,
                       W1, W2, W3, W4, W5, ws);
    hipLaunchKernelGGL(mlp_mfma, dim3(131072 / MROWS), dim3(NTHREADS), 0, stream,
                       x, b1, b2, b3, b4, b5, ws, out);
}